// Round 6
// baseline (53.000 us; speedup 1.0000x reference)
//
#include <hip/hip_runtime.h>
#include <math.h>

#define H 256
#define EPS 1e-4f

// ---- DPP helpers (gfx9/CDNA), bound_ctrl:0 (0-fill invalid lanes) ----
template <int CTRL>
__device__ __forceinline__ float dpp0(float x) {
    return __int_as_float(
        __builtin_amdgcn_update_dpp(0, __float_as_int(x), CTRL, 0xf, 0xf, true));
}
__device__ __forceinline__ float rdlane(float x, int l) {
    return __int_as_float(__builtin_amdgcn_readlane(__float_as_int(x), l));
}
__device__ __forceinline__ float frcp_fast(float v) { return __builtin_amdgcn_rcpf(v); }
__device__ __forceinline__ float frcp_nr(float v) {
    float r = __builtin_amdgcn_rcpf(v);
    return fmaf(r, fmaf(-v, r, 1.0f), r);
}
// full-wave sum of four values, result uniform
__device__ __forceinline__ void wave_red_sum4(float& a, float& b, float& c, float& d) {
    a += dpp0<0x111>(a); b += dpp0<0x111>(b); c += dpp0<0x111>(c); d += dpp0<0x111>(d);
    a += dpp0<0x112>(a); b += dpp0<0x112>(b); c += dpp0<0x112>(c); d += dpp0<0x112>(d);
    a += dpp0<0x114>(a); b += dpp0<0x114>(b); c += dpp0<0x114>(c); d += dpp0<0x114>(d);
    a += dpp0<0x118>(a); b += dpp0<0x118>(b); c += dpp0<0x118>(c); d += dpp0<0x118>(d);
    a += dpp0<0x142>(a); b += dpp0<0x142>(b); c += dpp0<0x142>(c); d += dpp0<0x142>(d);
    a += dpp0<0x143>(a); b += dpp0<0x143>(b); c += dpp0<0x143>(c); d += dpp0<0x143>(d);
    a = rdlane(a, 63); b = rdlane(b, 63); c = rdlane(c, 63); d = rdlane(d, 63);
}

struct Schur {
    float F[4], B[4], av[4], ra[4], x[4], R[4];
    float sF, sB, isB, sR;
};

// One Schur step with scalar lookahead; KF1=(k+1)&3, KF2=(k+2)&3 compile-time.
// Readlanes touch only previous-step vectors.
template <int KF1, int KF2>
__device__ __forceinline__ void schur_step(Schur& s, int LN1, int LN2) {
    float g  = -s.sF * s.isB;
    float sE = fmaf(g, s.sF, s.sB);          // B_{k+1}[k+1]
    s.isB = frcp_fast(sE);
    float mu = s.sR * s.isB;
    float rlF2 = rdlane(s.F[KF2], LN2);      // F_k[k+2]
    float rlB1 = rdlane(s.B[KF1], LN1);      // B_k[k+1]
    float rlR2 = rdlane(s.R[KF2], LN2);      // R_k[k+2]
    s.sF = fmaf(g, rlB1, rlF2);              // F_{k+1}[k+2]
    float tB2 = fmaf(g, rlF2, rlB1);         // B_{k+1}[k+2]
    s.sR = fmaf(-mu, tB2, rlR2);             // R_{k+1}[k+2]
    s.sB = sE;
    float sb0 = dpp0<0x138>(s.B[3]);         // wave_shr:1
    float sr0 = dpp0<0x138>(s.ra[3]);
    float nB0 = fmaf(g, s.F[0], sb0);
    float nB1 = fmaf(g, s.F[1], s.B[0]);
    float nB2 = fmaf(g, s.F[2], s.B[1]);
    float nB3 = fmaf(g, s.F[3], s.B[2]);
    float nF0 = fmaf(g, sb0,    s.F[0]);
    float nF1 = fmaf(g, s.B[0], s.F[1]);
    float nF2 = fmaf(g, s.B[1], s.F[2]);
    float nF3 = fmaf(g, s.B[2], s.F[3]);
    float nr0 = fmaf(g, s.av[0], sr0);
    float nr1 = fmaf(g, s.av[1], s.ra[0]);
    float nr2 = fmaf(g, s.av[2], s.ra[1]);
    float nr3 = fmaf(g, s.av[3], s.ra[2]);
    float na0 = fmaf(g, sr0,     s.av[0]);
    float na1 = fmaf(g, s.ra[0], s.av[1]);
    float na2 = fmaf(g, s.ra[1], s.av[2]);
    float na3 = fmaf(g, s.ra[2], s.av[3]);
    s.x[0] = fmaf(mu, nr0, s.x[0]);  s.R[0] = fmaf(-mu, nB0, s.R[0]);
    s.x[1] = fmaf(mu, nr1, s.x[1]);  s.R[1] = fmaf(-mu, nB1, s.R[1]);
    s.x[2] = fmaf(mu, nr2, s.x[2]);  s.R[2] = fmaf(-mu, nB2, s.R[2]);
    s.x[3] = fmaf(mu, nr3, s.x[3]);  s.R[3] = fmaf(-mu, nB3, s.R[3]);
    s.B[0]=nB0; s.B[1]=nB1; s.B[2]=nB2; s.B[3]=nB3;
    s.F[0]=nF0; s.F[1]=nF1; s.F[2]=nF2; s.F[3]=nF3;
    s.av[0]=na0; s.av[1]=na1; s.av[2]=na2; s.av[3]=na3;
    s.ra[0]=nr0; s.ra[1]=nr1; s.ra[2]=nr2; s.ra[3]=nr3;
}

__device__ __forceinline__ void schur_last(Schur& s) {   // k = 254: only x update
    float g  = -s.sF * s.isB;
    float sE = fmaf(g, s.sF, s.sB);
    float mu = s.sR * frcp_fast(sE);
    float sr0 = dpp0<0x138>(s.ra[3]);
    s.x[0] = fmaf(mu, fmaf(g, s.av[0], sr0),     s.x[0]);
    s.x[1] = fmaf(mu, fmaf(g, s.av[1], s.ra[0]), s.x[1]);
    s.x[2] = fmaf(mu, fmaf(g, s.av[2], s.ra[1]), s.x[2]);
    s.x[3] = fmaf(mu, fmaf(g, s.av[3], s.ra[2]), s.x[3]);
}

// init state from raw correlations (lane-major e = 4*lane+c)
__device__ __forceinline__ void schur_init(Schur& s, const float* racc,
                                           const float* bacc, bool l0) {
    float t0v = rdlane(racc[0], 0) + EPS;
    float it0 = frcp_nr(t0v);
    #pragma unroll
    for (int c = 0; c < 4; ++c) {
        float rh = racc[c] * it0;
        if (c == 0) rh = l0 ? 1.0f : rh;
        s.F[c] = rh; s.B[c] = rh;
    }
    float bb0 = rdlane(bacc[0], 0) * it0;
    #pragma unroll
    for (int c = 0; c < 4; ++c) {
        float bvv = bacc[c] * it0;
        s.R[c] = fmaf(-bb0, s.F[c], bvv);
        s.x[c] = 0.f; s.av[c] = 0.f; s.ra[c] = 0.f;
    }
    if (l0) { s.x[0] = bb0; s.av[0] = 1.0f; s.ra[0] = 1.0f; }
    s.sF  = rdlane(s.F[1], 0);
    s.sB  = 1.0f; s.isB = 1.0f;
    s.sR  = rdlane(s.R[1], 0);
}

// One wave per TWO batches: two interleaved Schur recursions fill each
// other's dependency stalls (1 wave/SIMD -> no TLP; this supplies the ILP).
__global__ __launch_bounds__(64) void awloss_batch(
        const float* __restrict__ recon,
        const float* __restrict__ target,
        float* __restrict__ losses) {
    const int bp   = blockIdx.x;          // batch pair
    const int b0   = 2 * bp, b1 = 2 * bp + 1;
    const int lane = threadIdx.x;
    const bool l0  = (lane == 0);

    __shared__ __align__(16) float tgtA[576], recA[576], tgtB[576], recB[576];

    const float4 tvA = ((const float4*)(target + b0 * H))[lane];
    const float4 rvA = ((const float4*)(recon  + b0 * H))[lane];
    const float4 tvB = ((const float4*)(target + b1 * H))[lane];
    const float4 rvB = ((const float4*)(recon  + b1 * H))[lane];

    #pragma unroll
    for (int c = 0; c < 9; ++c) {
        tgtA[c*64+lane] = 0.f; recA[c*64+lane] = 0.f;
        tgtB[c*64+lane] = 0.f; recB[c*64+lane] = 0.f;
    }
    __syncthreads();
    *(float4*)&tgtA[4*lane] = tvA;
    *(float4*)&tgtB[4*lane] = tvB;
    recA[127+4*lane+0]=rvA.x; recA[127+4*lane+1]=rvA.y;
    recA[127+4*lane+2]=rvA.z; recA[127+4*lane+3]=rvA.w;
    recB[127+4*lane+0]=rvB.x; recB[127+4*lane+1]=rvB.y;
    recB[127+4*lane+2]=rvB.z; recB[127+4*lane+3]=rvB.w;
    __syncthreads();

    // --- correlations for both batches, interleaved; d = 4*lane+c ---
    float raA[4]={0,0,0,0}, baA[4]={0,0,0,0}, raB[4]={0,0,0,0}, baB[4]={0,0,0,0};
    float4 WtA = *(const float4*)&tgtA[4*lane];
    float4 WrA = *(const float4*)&recA[4*lane];
    float4 WtB = *(const float4*)&tgtB[4*lane];
    float4 WrB = *(const float4*)&recB[4*lane];
    for (int m0 = 0; m0 < 256; m0 += 4) {
        float4 NtA = *(const float4*)&tgtA[m0 + 4 + 4*lane];
        float4 NrA = *(const float4*)&recA[m0 + 4 + 4*lane];
        float4 NtB = *(const float4*)&tgtB[m0 + 4 + 4*lane];
        float4 NrB = *(const float4*)&recB[m0 + 4 + 4*lane];
        float a0 = rdlane(WtA.x,0), a1 = rdlane(WtA.y,0),
              a2 = rdlane(WtA.z,0), a3 = rdlane(WtA.w,0);
        float b0s= rdlane(WtB.x,0), b1s= rdlane(WtB.y,0),
              b2s= rdlane(WtB.z,0), b3s= rdlane(WtB.w,0);
        // m = m0
        raA[0]=fmaf(a0,WtA.x,raA[0]); baA[0]=fmaf(a0,WrA.x,baA[0]);
        raB[0]=fmaf(b0s,WtB.x,raB[0]); baB[0]=fmaf(b0s,WrB.x,baB[0]);
        raA[1]=fmaf(a0,WtA.y,raA[1]); baA[1]=fmaf(a0,WrA.y,baA[1]);
        raB[1]=fmaf(b0s,WtB.y,raB[1]); baB[1]=fmaf(b0s,WrB.y,baB[1]);
        raA[2]=fmaf(a0,WtA.z,raA[2]); baA[2]=fmaf(a0,WrA.z,baA[2]);
        raB[2]=fmaf(b0s,WtB.z,raB[2]); baB[2]=fmaf(b0s,WrB.z,baB[2]);
        raA[3]=fmaf(a0,WtA.w,raA[3]); baA[3]=fmaf(a0,WrA.w,baA[3]);
        raB[3]=fmaf(b0s,WtB.w,raB[3]); baB[3]=fmaf(b0s,WrB.w,baB[3]);
        // m = m0+1
        raA[0]=fmaf(a1,WtA.y,raA[0]); baA[0]=fmaf(a1,WrA.y,baA[0]);
        raB[0]=fmaf(b1s,WtB.y,raB[0]); baB[0]=fmaf(b1s,WrB.y,baB[0]);
        raA[1]=fmaf(a1,WtA.z,raA[1]); baA[1]=fmaf(a1,WrA.z,baA[1]);
        raB[1]=fmaf(b1s,WtB.z,raB[1]); baB[1]=fmaf(b1s,WrB.z,baB[1]);
        raA[2]=fmaf(a1,WtA.w,raA[2]); baA[2]=fmaf(a1,WrA.w,baA[2]);
        raB[2]=fmaf(b1s,WtB.w,raB[2]); baB[2]=fmaf(b1s,WrB.w,baB[2]);
        raA[3]=fmaf(a1,NtA.x,raA[3]); baA[3]=fmaf(a1,NrA.x,baA[3]);
        raB[3]=fmaf(b1s,NtB.x,raB[3]); baB[3]=fmaf(b1s,NrB.x,baB[3]);
        // m = m0+2
        raA[0]=fmaf(a2,WtA.z,raA[0]); baA[0]=fmaf(a2,WrA.z,baA[0]);
        raB[0]=fmaf(b2s,WtB.z,raB[0]); baB[0]=fmaf(b2s,WrB.z,baB[0]);
        raA[1]=fmaf(a2,WtA.w,raA[1]); baA[1]=fmaf(a2,WrA.w,baA[1]);
        raB[1]=fmaf(b2s,WtB.w,raB[1]); baB[1]=fmaf(b2s,WrB.w,baB[1]);
        raA[2]=fmaf(a2,NtA.x,raA[2]); baA[2]=fmaf(a2,NrA.x,baA[2]);
        raB[2]=fmaf(b2s,NtB.x,raB[2]); baB[2]=fmaf(b2s,NrB.x,baB[2]);
        raA[3]=fmaf(a2,NtA.y,raA[3]); baA[3]=fmaf(a2,NrA.y,baA[3]);
        raB[3]=fmaf(b2s,NtB.y,raB[3]); baB[3]=fmaf(b2s,NrB.y,baB[3]);
        // m = m0+3
        raA[0]=fmaf(a3,WtA.w,raA[0]); baA[0]=fmaf(a3,WrA.w,baA[0]);
        raB[0]=fmaf(b3s,WtB.w,raB[0]); baB[0]=fmaf(b3s,WrB.w,baB[0]);
        raA[1]=fmaf(a3,NtA.x,raA[1]); baA[1]=fmaf(a3,NrA.x,baA[1]);
        raB[1]=fmaf(b3s,NtB.x,raB[1]); baB[1]=fmaf(b3s,NrB.x,baB[1]);
        raA[2]=fmaf(a3,NtA.y,raA[2]); baA[2]=fmaf(a3,NrA.y,baA[2]);
        raB[2]=fmaf(b3s,NtB.y,raB[2]); baB[2]=fmaf(b3s,NrB.y,baB[2]);
        raA[3]=fmaf(a3,NtA.z,raA[3]); baA[3]=fmaf(a3,NrA.z,baA[3]);
        raB[3]=fmaf(b3s,NtB.z,raB[3]); baB[3]=fmaf(b3s,NrB.z,baB[3]);
        WtA = NtA; WrA = NrA; WtB = NtB; WrB = NrB;
    }

    // --- two interleaved Schur recursions ---
    Schur sA, sB;
    schur_init(sA, raA, baA, l0);
    schur_init(sB, raB, baB, l0);

    for (int t = 0; t < 63; ++t) {
        schur_step<1,2>(sA, t, t);     schur_step<1,2>(sB, t, t);
        schur_step<2,3>(sA, t, t);     schur_step<2,3>(sB, t, t);
        schur_step<3,0>(sA, t, t+1);   schur_step<3,0>(sB, t, t+1);
        schur_step<0,1>(sA, t+1, t+1); schur_step<0,1>(sB, t+1, t+1);
    }
    schur_step<1,2>(sA, 63, 63);  schur_step<1,2>(sB, 63, 63);
    schur_step<2,3>(sA, 63, 63);  schur_step<2,3>(sB, 63, 63);
    schur_last(sA);               schur_last(sB);

    // --- losses ---
    float sTA = 0.f, sVA = 0.f, sTB = 0.f, sVB = 0.f;
    const float dxg = 20.0f / 255.0f;
    #pragma unroll
    for (int c = 0; c < 4; ++c) {
        float u  = -10.0f + dxg * (float)(4*lane + c) + 0.5f * dxg;
        float Ti = 1.0f - expf(-0.5f * u * u);
        float vA = sA.x[c], vB = sB.x[c];
        float tA = Ti * vA, tB = Ti * vB;
        sTA += tA * tA;  sVA += vA * vA;
        sTB += tB * tB;  sVB += vB * vB;
    }
    wave_red_sum4(sTA, sVA, sTB, sVB);
    if (l0) {
        losses[b0] = 0.5f * sqrtf(sTA / sVA);
        losses[b1] = 0.5f * sqrtf(sTB / sVB);
    }
}

// deterministic final reduction of 512 per-batch losses
__global__ __launch_bounds__(64) void awloss_reduce(
        const float* __restrict__ losses, float* __restrict__ out) {
    int lane = threadIdx.x;
    float s = 0.f;
    #pragma unroll
    for (int c = 0; c < 8; ++c) s += losses[c * 64 + lane];
    float d = 0.f, e = 0.f, f = 0.f;
    wave_red_sum4(s, d, e, f);
    if (lane == 0) out[0] = s;
}

extern "C" void kernel_launch(void* const* d_in, const int* in_sizes, int n_in,
                              void* d_out, int out_size, void* d_ws, size_t ws_size,
                              hipStream_t stream) {
    const float* recon  = (const float*)d_in[0];
    const float* target = (const float*)d_in[1];
    float* losses = (float*)d_ws;   // 512 floats
    float* out    = (float*)d_out;

    awloss_batch<<<256, 64, 0, stream>>>(recon, target, losses);
    awloss_reduce<<<1, 64, 0, stream>>>(losses, out);
}

// Round 7
// 39.616 us; speedup vs baseline: 1.3379x; 1.3379x over previous
//
#include <hip/hip_runtime.h>
#include <math.h>

#define H 256
#define EPS 1e-4f

// ---- DPP helpers (gfx9/CDNA), bound_ctrl:0 (0-fill invalid lanes) ----
template <int CTRL>
__device__ __forceinline__ float dpp0(float x) {
    return __int_as_float(
        __builtin_amdgcn_update_dpp(0, __float_as_int(x), CTRL, 0xf, 0xf, true));
}
__device__ __forceinline__ float rdlane(float x, int l) {
    return __int_as_float(__builtin_amdgcn_readlane(__float_as_int(x), l));
}
__device__ __forceinline__ float frcp_fast(float v) { return __builtin_amdgcn_rcpf(v); }
__device__ __forceinline__ float frcp_nr(float v) {
    float r = __builtin_amdgcn_rcpf(v);
    return fmaf(r, fmaf(-v, r, 1.0f), r);
}
__device__ __forceinline__ void wave_red_sum2(float& a, float& b) {
    a += dpp0<0x111>(a);  b += dpp0<0x111>(b);
    a += dpp0<0x112>(a);  b += dpp0<0x112>(b);
    a += dpp0<0x114>(a);  b += dpp0<0x114>(b);
    a += dpp0<0x118>(a);  b += dpp0<0x118>(b);
    a += dpp0<0x142>(a);  b += dpp0<0x142>(b);
    a += dpp0<0x143>(a);  b += dpp0<0x143>(b);
    a = rdlane(a, 63);
    b = rdlane(b, 63);
}

// Producer-side Schur step (F,B,R + scalar lookahead chain), publishes (g,mu).
// KF1=(k+1)&3, KF2=(k+2)&3 literals; LN1/LN2 SGPR; K = step index for gmu.
#define PSTEP(KF1, KF2, LN1, LN2, K) do {                               \
    float g  = -sF * isB;                                               \
    float sE = fmaf(g, sF, sB);              /* B_{k+1}[k+1] */         \
    isB = frcp_fast(sE);                                                \
    float mu = sR * isB;                                                \
    if (l0) gmu[(K)] = make_float2(g, mu);                              \
    float rlF2 = rdlane(F[KF2], (LN2));      /* F_k[k+2] */             \
    float rlB1 = rdlane(B[KF1], (LN1));      /* B_k[k+1] */             \
    float rlR2 = rdlane(R[KF2], (LN2));      /* R_k[k+2] */             \
    sF = fmaf(g, rlB1, rlF2);                                           \
    float tB2 = fmaf(g, rlF2, rlB1);                                    \
    sR = fmaf(-mu, tB2, rlR2);                                          \
    sB = sE;                                                            \
    float sb0 = dpp0<0x138>(B[3]);           /* wave_shr:1 */           \
    float nB0 = fmaf(g, F[0], sb0);                                     \
    float nB1 = fmaf(g, F[1], B[0]);                                    \
    float nB2 = fmaf(g, F[2], B[1]);                                    \
    float nB3 = fmaf(g, F[3], B[2]);                                    \
    float nF0 = fmaf(g, sb0,  F[0]);                                    \
    float nF1 = fmaf(g, B[0], F[1]);                                    \
    float nF2 = fmaf(g, B[1], F[2]);                                    \
    float nF3 = fmaf(g, B[2], F[3]);                                    \
    R[0] = fmaf(-mu, nB0, R[0]);                                        \
    R[1] = fmaf(-mu, nB1, R[1]);                                        \
    R[2] = fmaf(-mu, nB2, R[2]);                                        \
    R[3] = fmaf(-mu, nB3, R[3]);                                        \
    B[0]=nB0; B[1]=nB1; B[2]=nB2; B[3]=nB3;                             \
    F[0]=nF0; F[1]=nF1; F[2]=nF2; F[3]=nF3;                             \
} while (0)

// Consumer-side step: x,a,ra from a published (g,mu) pair.
#define CSTEP(G, MU) do {                                               \
    float g = (G), mu = (MU);                                           \
    float sr0 = dpp0<0x138>(ra[3]);                                     \
    float nr0 = fmaf(g, a[0], sr0);                                     \
    float nr1 = fmaf(g, a[1], ra[0]);                                   \
    float nr2 = fmaf(g, a[2], ra[1]);                                   \
    float nr3 = fmaf(g, a[3], ra[2]);                                   \
    float na0 = fmaf(g, sr0,  a[0]);                                    \
    float na1 = fmaf(g, ra[0], a[1]);                                   \
    float na2 = fmaf(g, ra[1], a[2]);                                   \
    float na3 = fmaf(g, ra[2], a[3]);                                   \
    x[0] = fmaf(mu, nr0, x[0]);                                         \
    x[1] = fmaf(mu, nr1, x[1]);                                         \
    x[2] = fmaf(mu, nr2, x[2]);                                         \
    x[3] = fmaf(mu, nr3, x[3]);                                         \
    a[0]=na0; a[1]=na1; a[2]=na2; a[3]=na3;                             \
    ra[0]=nr0; ra[1]=nr1; ra[2]=nr2; ra[3]=nr3;                         \
} while (0)

// 2 waves per batch: wave0 = producer (F,B,R + scalar chain -> (g,mu) stream),
// wave1 = consumer (x,a,ra + loss), one-directional LDS stream, no barriers
// in the recursion.
__global__ __launch_bounds__(128) void awloss_batch(
        const float* __restrict__ recon,
        const float* __restrict__ target,
        float* __restrict__ losses) {
    const int b    = blockIdx.x;
    const int tid  = threadIdx.x;
    const int lane = tid & 63;
    const int wid  = tid >> 6;
    const bool l0  = (lane == 0);

    __shared__ __align__(16) float tgtp[576];   // target, zero-padded
    __shared__ __align__(16) float recp[576];   // recon at [127..382], zeros else
    __shared__ __align__(16) float accR[256];   // autocorr  (published by wave0)
    __shared__ __align__(16) float accBs[256];  // cross-corr (published by wave1)
    __shared__ float2 gmu[256];                 // (g, mu) stream
    __shared__ int done;

    if (tid == 0) done = -1;
    #pragma unroll
    for (int c = 0; c < 5; ++c) {
        int i = c * 128 + tid;
        if (i < 576) { tgtp[i] = 0.f; recp[i] = 0.f; }
    }
    __syncthreads();
    if (wid == 0) {
        float4 tv4 = ((const float4*)(target + b * H))[lane];
        *(float4*)&tgtp[4 * lane] = tv4;
    } else {
        float4 rv4 = ((const float4*)(recon + b * H))[lane];
        recp[127 + 4*lane + 0] = rv4.x;
        recp[127 + 4*lane + 1] = rv4.y;
        recp[127 + 4*lane + 2] = rv4.z;
        recp[127 + 4*lane + 3] = rv4.w;
    }
    __syncthreads();

    // --- correlation: wave0 -> racc (window=tgtp), wave1 -> bacc (window=recp);
    //     t[m] quad via uniform broadcast b128 read; identical fma order to R5 ---
    const float* W = (wid == 0) ? tgtp : recp;
    float acc[4] = {0.f, 0.f, 0.f, 0.f};
    float4 W0 = *(const float4*)&W[4 * lane];
    for (int m0 = 0; m0 < 256; m0 += 4) {
        float4 N  = *(const float4*)&W[m0 + 4 + 4 * lane];
        float4 tq = *(const float4*)&tgtp[m0];           // uniform broadcast
        acc[0]=fmaf(tq.x,W0.x,acc[0]); acc[1]=fmaf(tq.x,W0.y,acc[1]);
        acc[2]=fmaf(tq.x,W0.z,acc[2]); acc[3]=fmaf(tq.x,W0.w,acc[3]);
        acc[0]=fmaf(tq.y,W0.y,acc[0]); acc[1]=fmaf(tq.y,W0.z,acc[1]);
        acc[2]=fmaf(tq.y,W0.w,acc[2]); acc[3]=fmaf(tq.y,N.x ,acc[3]);
        acc[0]=fmaf(tq.z,W0.z,acc[0]); acc[1]=fmaf(tq.z,W0.w,acc[1]);
        acc[2]=fmaf(tq.z,N.x ,acc[2]); acc[3]=fmaf(tq.z,N.y ,acc[3]);
        acc[0]=fmaf(tq.w,W0.w,acc[0]); acc[1]=fmaf(tq.w,N.x ,acc[1]);
        acc[2]=fmaf(tq.w,N.y ,acc[2]); acc[3]=fmaf(tq.w,N.z ,acc[3]);
        W0 = N;
    }
    if (wid == 0) *(float4*)&accR [4*lane] = make_float4(acc[0],acc[1],acc[2],acc[3]);
    else          *(float4*)&accBs[4*lane] = make_float4(acc[0],acc[1],acc[2],acc[3]);
    __syncthreads();
    // ---- no barriers below this line; waves fully diverge ----

    if (wid == 0) {
        // ================= producer =================
        float t0v = rdlane(acc[0], 0) + EPS;      // acc == racc
        float it0 = frcp_nr(t0v);
        float F[4], B[4], R[4];
        #pragma unroll
        for (int c = 0; c < 4; ++c) {
            float rh = acc[c] * it0;
            if (c == 0) rh = l0 ? 1.0f : rh;
            F[c] = rh; B[c] = rh;
        }
        float4 bb4 = *(const float4*)&accBs[4 * lane];
        float bb0 = rdlane(bb4.x, 0) * it0;
        R[0] = fmaf(-bb0, F[0], bb4.x * it0);
        R[1] = fmaf(-bb0, F[1], bb4.y * it0);
        R[2] = fmaf(-bb0, F[2], bb4.z * it0);
        R[3] = fmaf(-bb0, F[3], bb4.w * it0);

        float sF  = rdlane(F[1], 0);
        float sB  = 1.0f, isB = 1.0f;
        float sR  = rdlane(R[1], 0);

        for (int t = 0; t < 63; ++t) {
            int k = 4 * t;
            PSTEP(1, 2, t,     t,     k    );
            PSTEP(2, 3, t,     t,     k + 1);
            PSTEP(3, 0, t,     t + 1, k + 2);
            PSTEP(0, 1, t + 1, t + 1, k + 3);
            if (t & 1)
                if (l0) __hip_atomic_store(&done, k + 3, __ATOMIC_RELEASE,
                                           __HIP_MEMORY_SCOPE_WORKGROUP);
        }
        PSTEP(1, 2, 63, 63, 252);
        PSTEP(2, 3, 63, 63, 253);
        {   // k = 254: scalars only
            float g  = -sF * isB;
            float sE = fmaf(g, sF, sB);
            float mu = sR * frcp_fast(sE);
            if (l0) gmu[254] = make_float2(g, mu);
        }
        if (l0) __hip_atomic_store(&done, 255, __ATOMIC_RELEASE,
                                   __HIP_MEMORY_SCOPE_WORKGROUP);
    } else {
        // ================= consumer =================
        float t0v = accR[0] + EPS;                // uniform LDS read
        float it0 = frcp_nr(t0v);
        float bb0 = rdlane(acc[0], 0) * it0;      // acc == bacc
        float x[4]  = {0.f,0.f,0.f,0.f};
        float a[4]  = {0.f,0.f,0.f,0.f};
        float ra[4] = {0.f,0.f,0.f,0.f};
        if (l0) { x[0] = bb0; a[0] = 1.0f; ra[0] = 1.0f; }

        for (int T = 0; T < 31; ++T) {
            int tgt_step = 8 * T + 7;
            while (__hip_atomic_load(&done, __ATOMIC_ACQUIRE,
                                     __HIP_MEMORY_SCOPE_WORKGROUP) < tgt_step) {}
            float2 gm8 = gmu[8 * T + (lane & 7)];
            #pragma unroll
            for (int s = 0; s < 8; ++s)
                CSTEP(rdlane(gm8.x, s), rdlane(gm8.y, s));
        }
        while (__hip_atomic_load(&done, __ATOMIC_ACQUIRE,
                                 __HIP_MEMORY_SCOPE_WORKGROUP) < 254) {}
        float2 gm8 = gmu[248 + (lane & 7)];
        #pragma unroll
        for (int s = 0; s < 7; ++s)
            CSTEP(rdlane(gm8.x, s), rdlane(gm8.y, s));

        // --- loss: 0.5*sqrt(sum((T*v)^2)/sum(v^2)), elements e = 4*lane+c ---
        float sT = 0.f, sV = 0.f;
        const float dxg = 20.0f / 255.0f;
        #pragma unroll
        for (int c = 0; c < 4; ++c) {
            float v  = x[c];
            float u  = -10.0f + dxg * (float)(4*lane + c) + 0.5f * dxg;
            float Ti = 1.0f - expf(-0.5f * u * u);   // T normalizers == 1.0f
            float tw = Ti * v;
            sT += tw * tw;
            sV += v * v;
        }
        wave_red_sum2(sT, sV);
        if (l0) losses[b] = 0.5f * sqrtf(sT / sV);
    }
}

// deterministic final reduction of 512 per-batch losses
__global__ __launch_bounds__(64) void awloss_reduce(
        const float* __restrict__ losses, float* __restrict__ out) {
    int lane = threadIdx.x;
    float s = 0.f;
    #pragma unroll
    for (int c = 0; c < 8; ++c) s += losses[c * 64 + lane];
    float d = 0.f;
    wave_red_sum2(s, d);
    if (lane == 0) out[0] = s;
}

extern "C" void kernel_launch(void* const* d_in, const int* in_sizes, int n_in,
                              void* d_out, int out_size, void* d_ws, size_t ws_size,
                              hipStream_t stream) {
    const float* recon  = (const float*)d_in[0];
    const float* target = (const float*)d_in[1];
    float* losses = (float*)d_ws;   // 512 floats
    float* out    = (float*)d_out;

    awloss_batch<<<512, 128, 0, stream>>>(recon, target, losses);
    awloss_reduce<<<1, 64, 0, stream>>>(losses, out);
}

// Round 8
// 35.995 us; speedup vs baseline: 1.4724x; 1.1006x over previous
//
#include <hip/hip_runtime.h>
#include <math.h>

#define H 256
#define EPS 1e-4f
#define MAGIC 0xC0FFEE42u

// ---- DPP helpers (gfx9/CDNA), bound_ctrl:0 (0-fill invalid lanes) ----
template <int CTRL>
__device__ __forceinline__ float dpp0(float x) {
    return __int_as_float(
        __builtin_amdgcn_update_dpp(0, __float_as_int(x), CTRL, 0xf, 0xf, true));
}
__device__ __forceinline__ float rdlane(float x, int l) {
    return __int_as_float(__builtin_amdgcn_readlane(__float_as_int(x), l));
}
__device__ __forceinline__ float frcp_fast(float v) { return __builtin_amdgcn_rcpf(v); }
__device__ __forceinline__ float frcp_nr(float v) {
    float r = __builtin_amdgcn_rcpf(v);
    return fmaf(r, fmaf(-v, r, 1.0f), r);
}
// full-wave sum of two values, result uniform
__device__ __forceinline__ void wave_red_sum2(float& a, float& b) {
    a += dpp0<0x111>(a);  b += dpp0<0x111>(b);
    a += dpp0<0x112>(a);  b += dpp0<0x112>(b);
    a += dpp0<0x114>(a);  b += dpp0<0x114>(b);
    a += dpp0<0x118>(a);  b += dpp0<0x118>(b);
    a += dpp0<0x142>(a);  b += dpp0<0x142>(b);
    a += dpp0<0x143>(a);  b += dpp0<0x143>(b);
    a = rdlane(a, 63);
    b = rdlane(b, 63);
}

// Schur step k with scalar lookahead. KF1=(k+1)&3, KF2=(k+2)&3 literals;
// LN1=(k+1)>>2, LN2=(k+2)>>2 runtime (SGPR). Scalars sF,sB,isB,sR carried
// across steps; readlanes touch only PREVIOUS-step vectors, so the scalar
// chain (fma->rcp->mul) never waits on this step's vector fmas.
#define STEP(KF1, KF2, LN1, LN2) do {                                   \
    float g  = -sF * isB;                                               \
    float sE = fmaf(g, sF, sB);              /* B_{k+1}[k+1] */         \
    isB = frcp_fast(sE);                                                \
    float mu = sR * isB;                                                \
    float rlF2 = rdlane(F[KF2], (LN2));      /* F_k[k+2] */             \
    float rlB1 = rdlane(Bv[KF1], (LN1));     /* B_k[k+1] */             \
    float rlR2 = rdlane(Rv[KF2], (LN2));     /* R_k[k+2] */             \
    sF = fmaf(g, rlB1, rlF2);                /* F_{k+1}[k+2] */         \
    float tB2 = fmaf(g, rlF2, rlB1);         /* B_{k+1}[k+2] */         \
    sR = fmaf(-mu, tB2, rlR2);               /* R_{k+1}[k+2] */         \
    sB = sE;                                                            \
    float sb0 = dpp0<0x138>(Bv[3]);          /* wave_shr:1 */           \
    float sr0 = dpp0<0x138>(rav[3]);                                    \
    float nB0 = fmaf(g, F[0], sb0);                                     \
    float nB1 = fmaf(g, F[1], Bv[0]);                                   \
    float nB2 = fmaf(g, F[2], Bv[1]);                                   \
    float nB3 = fmaf(g, F[3], Bv[2]);                                   \
    float nF0 = fmaf(g, sb0,  F[0]);                                    \
    float nF1 = fmaf(g, Bv[0], F[1]);                                   \
    float nF2 = fmaf(g, Bv[1], F[2]);                                   \
    float nF3 = fmaf(g, Bv[2], F[3]);                                   \
    float nr0 = fmaf(g, av[0], sr0);                                    \
    float nr1 = fmaf(g, av[1], rav[0]);                                 \
    float nr2 = fmaf(g, av[2], rav[1]);                                 \
    float nr3 = fmaf(g, av[3], rav[2]);                                 \
    float na0 = fmaf(g, sr0,   av[0]);                                  \
    float na1 = fmaf(g, rav[0], av[1]);                                 \
    float na2 = fmaf(g, rav[1], av[2]);                                 \
    float na3 = fmaf(g, rav[2], av[3]);                                 \
    xv[0] = fmaf(mu, nr0, xv[0]);  Rv[0] = fmaf(-mu, nB0, Rv[0]);       \
    xv[1] = fmaf(mu, nr1, xv[1]);  Rv[1] = fmaf(-mu, nB1, Rv[1]);       \
    xv[2] = fmaf(mu, nr2, xv[2]);  Rv[2] = fmaf(-mu, nB2, Rv[2]);       \
    xv[3] = fmaf(mu, nr3, xv[3]);  Rv[3] = fmaf(-mu, nB3, Rv[3]);       \
    Bv[0]=nB0; Bv[1]=nB1; Bv[2]=nB2; Bv[3]=nB3;                         \
    F[0]=nF0; F[1]=nF1; F[2]=nF2; F[3]=nF3;                             \
    av[0]=na0; av[1]=na1; av[2]=na2; av[3]=na3;                         \
    rav[0]=nr0; rav[1]=nr1; rav[2]=nr2; rav[3]=nr3;                     \
} while (0)

// One wave per batch. Schur solve of symmetric Toeplitz A v = b.
// Block 0 fuses the deterministic final sum via tag-validated spin reads
// (no counter, no reset: stale values from a previous replay are identical
// by determinism; poison/garbage fail the MAGIC tag with prob ~2^-32).
__global__ __launch_bounds__(64) void awloss_all(
        const float* __restrict__ recon,
        const float* __restrict__ target,
        unsigned long long* __restrict__ losses,
        float* __restrict__ out) {
    const int b    = blockIdx.x;
    const int lane = threadIdx.x;
    const bool l0  = (lane == 0);

    __shared__ __align__(16) float tgtp[576];   // t padded with zeros
    __shared__ __align__(16) float recp[576];   // rec at [127..382], zeros else

    const float4 tv4 = ((const float4*)(target + b * H))[lane];
    const float4 rv4 = ((const float4*)(recon  + b * H))[lane];

    #pragma unroll
    for (int c = 0; c < 9; ++c) { tgtp[c*64+lane] = 0.f; recp[c*64+lane] = 0.f; }
    __syncthreads();
    *(float4*)&tgtp[4*lane] = tv4;
    recp[127 + 4*lane + 0] = rv4.x;
    recp[127 + 4*lane + 1] = rv4.y;
    recp[127 + 4*lane + 2] = rv4.z;
    recp[127 + 4*lane + 3] = rv4.w;
    __syncthreads();

    // --- correlation r[d], b[d], lane-major d = 4*lane+c; b128 sliding window ---
    float racc[4] = {0.f,0.f,0.f,0.f}, bacc[4] = {0.f,0.f,0.f,0.f};
    float4 W0t = *(const float4*)&tgtp[4*lane];
    float4 W0r = *(const float4*)&recp[4*lane];
    for (int m0 = 0; m0 < 256; m0 += 4) {
        float4 W1t = *(const float4*)&tgtp[m0 + 4 + 4*lane];
        float4 W1r = *(const float4*)&recp[m0 + 4 + 4*lane];
        float t0s = rdlane(W0t.x, 0);
        float t1s = rdlane(W0t.y, 0);
        float t2s = rdlane(W0t.z, 0);
        float t3s = rdlane(W0t.w, 0);
        racc[0] = fmaf(t0s, W0t.x, racc[0]); bacc[0] = fmaf(t0s, W0r.x, bacc[0]);
        racc[1] = fmaf(t0s, W0t.y, racc[1]); bacc[1] = fmaf(t0s, W0r.y, bacc[1]);
        racc[2] = fmaf(t0s, W0t.z, racc[2]); bacc[2] = fmaf(t0s, W0r.z, bacc[2]);
        racc[3] = fmaf(t0s, W0t.w, racc[3]); bacc[3] = fmaf(t0s, W0r.w, bacc[3]);
        racc[0] = fmaf(t1s, W0t.y, racc[0]); bacc[0] = fmaf(t1s, W0r.y, bacc[0]);
        racc[1] = fmaf(t1s, W0t.z, racc[1]); bacc[1] = fmaf(t1s, W0r.z, bacc[1]);
        racc[2] = fmaf(t1s, W0t.w, racc[2]); bacc[2] = fmaf(t1s, W0r.w, bacc[2]);
        racc[3] = fmaf(t1s, W1t.x, racc[3]); bacc[3] = fmaf(t1s, W1r.x, bacc[3]);
        racc[0] = fmaf(t2s, W0t.z, racc[0]); bacc[0] = fmaf(t2s, W0r.z, bacc[0]);
        racc[1] = fmaf(t2s, W0t.w, racc[1]); bacc[1] = fmaf(t2s, W0r.w, bacc[1]);
        racc[2] = fmaf(t2s, W1t.x, racc[2]); bacc[2] = fmaf(t2s, W1r.x, bacc[2]);
        racc[3] = fmaf(t2s, W1t.y, racc[3]); bacc[3] = fmaf(t2s, W1r.y, bacc[3]);
        racc[0] = fmaf(t3s, W0t.w, racc[0]); bacc[0] = fmaf(t3s, W0r.w, bacc[0]);
        racc[1] = fmaf(t3s, W1t.x, racc[1]); bacc[1] = fmaf(t3s, W1r.x, bacc[1]);
        racc[2] = fmaf(t3s, W1t.y, racc[2]); bacc[2] = fmaf(t3s, W1r.y, bacc[2]);
        racc[3] = fmaf(t3s, W1t.z, racc[3]); bacc[3] = fmaf(t3s, W1r.z, bacc[3]);
        W0t = W1t; W0r = W1r;
    }

    // --- normalize; init Schur state directly in lane-major registers ---
    float t0v = rdlane(racc[0], 0) + EPS;
    float it0 = frcp_nr(t0v);
    float F[4], Bv[4], av[4], rav[4], xv[4], Rv[4];
    #pragma unroll
    for (int c = 0; c < 4; ++c) {
        float rh = racc[c] * it0;
        if (c == 0) rh = l0 ? 1.0f : rh;   // rho[0] = (r0+eps)/t0 = 1 exactly
        F[c] = rh; Bv[c] = rh;
    }
    float bb0 = rdlane(bacc[0], 0) * it0;
    #pragma unroll
    for (int c = 0; c < 4; ++c) {
        float bvv = bacc[c] * it0;
        Rv[c] = fmaf(-bb0, F[c], bvv);     // R_0 = bb - bb0*rho
        xv[c] = 0.f; av[c] = 0.f; rav[c] = 0.f;
    }
    if (l0) { xv[0] = bb0; av[0] = 1.0f; rav[0] = 1.0f; }

    float sF  = rdlane(F[1], 0);           // F_0[1] = rho[1]
    float sB  = 1.0f, isB = 1.0f;
    float sR  = rdlane(Rv[1], 0);          // R_0[1]

    // --- 255 Schur steps, x4 unrolled for literal register indices ---
    for (int t = 0; t < 63; ++t) {
        STEP(1, 2, t, t);                  // k = 4t
        STEP(2, 3, t, t);                  // k = 4t+1
        STEP(3, 0, t, t + 1);              // k = 4t+2
        STEP(0, 1, t + 1, t + 1);          // k = 4t+3
    }
    STEP(1, 2, 63, 63);                    // k = 252
    STEP(2, 3, 63, 63);                    // k = 253
    {   // k = 254: only mu and the x update matter
        float g  = -sF * isB;
        float sE = fmaf(g, sF, sB);
        float mu = sR * frcp_fast(sE);
        float sr0 = dpp0<0x138>(rav[3]);
        xv[0] = fmaf(mu, fmaf(g, av[0], sr0),    xv[0]);
        xv[1] = fmaf(mu, fmaf(g, av[1], rav[0]), xv[1]);
        xv[2] = fmaf(mu, fmaf(g, av[2], rav[1]), xv[2]);
        xv[3] = fmaf(mu, fmaf(g, av[3], rav[2]), xv[3]);
    }

    // --- loss: 0.5*sqrt(sum((T*v)^2)/sum(v^2)), elements e = 4*lane+c ---
    float sT = 0.f, sV = 0.f;
    const float dxg = 20.0f / 255.0f;
    #pragma unroll
    for (int c = 0; c < 4; ++c) {
        float v  = xv[c];
        float u  = -10.0f + dxg * (float)(4*lane + c) + 0.5f * dxg;
        float Ti = 1.0f - expf(-0.5f * u * u);   // T normalizers == 1.0f in f32
        float tw = Ti * v;
        sT += tw * tw;
        sV += v * v;
    }
    wave_red_sum2(sT, sV);
    if (l0) {
        float loss = 0.5f * sqrtf(sT / sV);
        unsigned long long pk =
            ((unsigned long long)MAGIC << 32) | (unsigned long long)__float_as_uint(loss);
        __hip_atomic_store(&losses[b], pk, __ATOMIC_RELEASE, __HIP_MEMORY_SCOPE_AGENT);
    }

    // --- block 0: fused deterministic final sum (fixed order, same as before) ---
    if (b == 0) {
        float s = 0.f;
        #pragma unroll
        for (int c = 0; c < 8; ++c) {
            int i = c * 64 + lane;
            unsigned long long pk;
            do {
                pk = __hip_atomic_load(&losses[i], __ATOMIC_ACQUIRE,
                                       __HIP_MEMORY_SCOPE_AGENT);
            } while ((unsigned)(pk >> 32) != MAGIC);
            s += __uint_as_float((unsigned)(pk & 0xFFFFFFFFu));
        }
        float d = 0.f;
        wave_red_sum2(s, d);
        if (l0) out[0] = s;
    }
}

extern "C" void kernel_launch(void* const* d_in, const int* in_sizes, int n_in,
                              void* d_out, int out_size, void* d_ws, size_t ws_size,
                              hipStream_t stream) {
    const float* recon  = (const float*)d_in[0];
    const float* target = (const float*)d_in[1];
    unsigned long long* losses = (unsigned long long*)d_ws;   // 512 x 8B tagged
    float* out = (float*)d_out;

    awloss_all<<<512, 64, 0, stream>>>(recon, target, losses, out);
}

// Round 9
// 30.946 us; speedup vs baseline: 1.7126x; 1.1631x over previous
//
#include <hip/hip_runtime.h>
#include <math.h>

#define H 256
#define EPS 1e-4f

// ---- DPP helpers (gfx9/CDNA), bound_ctrl:0 (0-fill invalid lanes) ----
template <int CTRL>
__device__ __forceinline__ float dpp0(float x) {
    return __int_as_float(
        __builtin_amdgcn_update_dpp(0, __float_as_int(x), CTRL, 0xf, 0xf, true));
}
__device__ __forceinline__ float rdlane(float x, int l) {
    return __int_as_float(__builtin_amdgcn_readlane(__float_as_int(x), l));
}
__device__ __forceinline__ float frcp_fast(float v) { return __builtin_amdgcn_rcpf(v); }
__device__ __forceinline__ float frcp_nr(float v) {
    float r = __builtin_amdgcn_rcpf(v);
    return fmaf(r, fmaf(-v, r, 1.0f), r);
}
// full-wave sum of two values, result uniform
__device__ __forceinline__ void wave_red_sum2(float& a, float& b) {
    a += dpp0<0x111>(a);  b += dpp0<0x111>(b);
    a += dpp0<0x112>(a);  b += dpp0<0x112>(b);
    a += dpp0<0x114>(a);  b += dpp0<0x114>(b);
    a += dpp0<0x118>(a);  b += dpp0<0x118>(b);
    a += dpp0<0x142>(a);  b += dpp0<0x142>(b);
    a += dpp0<0x143>(a);  b += dpp0<0x143>(b);
    a = rdlane(a, 63);
    b = rdlane(b, 63);
}

// Schur step k with scalar lookahead. KF1=(k+1)&3, KF2=(k+2)&3 literals;
// LN1=(k+1)>>2, LN2=(k+2)>>2 — LITERAL after full unroll, so readlanes use
// inline constant lane indices and can be hoisted freely by the scheduler.
#define STEP(KF1, KF2, LN1, LN2) do {                                   \
    float g  = -sF * isB;                                               \
    float sE = fmaf(g, sF, sB);              /* B_{k+1}[k+1] */         \
    isB = frcp_fast(sE);                                                \
    float mu = sR * isB;                                                \
    float rlF2 = rdlane(F[KF2], (LN2));      /* F_k[k+2] */             \
    float rlB1 = rdlane(Bv[KF1], (LN1));     /* B_k[k+1] */             \
    float rlR2 = rdlane(Rv[KF2], (LN2));     /* R_k[k+2] */             \
    sF = fmaf(g, rlB1, rlF2);                /* F_{k+1}[k+2] */         \
    float tB2 = fmaf(g, rlF2, rlB1);         /* B_{k+1}[k+2] */         \
    sR = fmaf(-mu, tB2, rlR2);               /* R_{k+1}[k+2] */         \
    sB = sE;                                                            \
    float sb0 = dpp0<0x138>(Bv[3]);          /* wave_shr:1 */           \
    float sr0 = dpp0<0x138>(rav[3]);                                    \
    float nB0 = fmaf(g, F[0], sb0);                                     \
    float nB1 = fmaf(g, F[1], Bv[0]);                                   \
    float nB2 = fmaf(g, F[2], Bv[1]);                                   \
    float nB3 = fmaf(g, F[3], Bv[2]);                                   \
    float nF0 = fmaf(g, sb0,  F[0]);                                    \
    float nF1 = fmaf(g, Bv[0], F[1]);                                   \
    float nF2 = fmaf(g, Bv[1], F[2]);                                   \
    float nF3 = fmaf(g, Bv[2], F[3]);                                   \
    float nr0 = fmaf(g, av[0], sr0);                                    \
    float nr1 = fmaf(g, av[1], rav[0]);                                 \
    float nr2 = fmaf(g, av[2], rav[1]);                                 \
    float nr3 = fmaf(g, av[3], rav[2]);                                 \
    float na0 = fmaf(g, sr0,   av[0]);                                  \
    float na1 = fmaf(g, rav[0], av[1]);                                 \
    float na2 = fmaf(g, rav[1], av[2]);                                 \
    float na3 = fmaf(g, rav[2], av[3]);                                 \
    xv[0] = fmaf(mu, nr0, xv[0]);  Rv[0] = fmaf(-mu, nB0, Rv[0]);       \
    xv[1] = fmaf(mu, nr1, xv[1]);  Rv[1] = fmaf(-mu, nB1, Rv[1]);       \
    xv[2] = fmaf(mu, nr2, xv[2]);  Rv[2] = fmaf(-mu, nB2, Rv[2]);       \
    xv[3] = fmaf(mu, nr3, xv[3]);  Rv[3] = fmaf(-mu, nB3, Rv[3]);       \
    Bv[0]=nB0; Bv[1]=nB1; Bv[2]=nB2; Bv[3]=nB3;                         \
    F[0]=nF0; F[1]=nF1; F[2]=nF2; F[3]=nF3;                             \
    av[0]=na0; av[1]=na1; av[2]=na2; av[3]=na3;                         \
    rav[0]=nr0; rav[1]=nr1; rav[2]=nr2; rav[3]=nr3;                     \
} while (0)

// One wave per batch. Schur solve of symmetric Toeplitz A v = b.
__global__ __launch_bounds__(64) void awloss_batch(
        const float* __restrict__ recon,
        const float* __restrict__ target,
        float* __restrict__ losses) {
    const int b    = blockIdx.x;
    const int lane = threadIdx.x;
    const bool l0  = (lane == 0);

    __shared__ __align__(16) float tgtp[576];   // t padded with zeros
    __shared__ __align__(16) float recp[576];   // rec at [127..382], zeros else

    const float4 tv4 = ((const float4*)(target + b * H))[lane];
    const float4 rv4 = ((const float4*)(recon  + b * H))[lane];

    #pragma unroll
    for (int c = 0; c < 9; ++c) { tgtp[c*64+lane] = 0.f; recp[c*64+lane] = 0.f; }
    __syncthreads();
    *(float4*)&tgtp[4*lane] = tv4;
    recp[127 + 4*lane + 0] = rv4.x;
    recp[127 + 4*lane + 1] = rv4.y;
    recp[127 + 4*lane + 2] = rv4.z;
    recp[127 + 4*lane + 3] = rv4.w;
    __syncthreads();

    // --- correlation r[d], b[d], lane-major d = 4*lane+c; b128 sliding window ---
    float racc[4] = {0.f,0.f,0.f,0.f}, bacc[4] = {0.f,0.f,0.f,0.f};
    float4 W0t = *(const float4*)&tgtp[4*lane];
    float4 W0r = *(const float4*)&recp[4*lane];
    for (int m0 = 0; m0 < 256; m0 += 4) {
        float4 W1t = *(const float4*)&tgtp[m0 + 4 + 4*lane];
        float4 W1r = *(const float4*)&recp[m0 + 4 + 4*lane];
        float t0s = rdlane(W0t.x, 0);
        float t1s = rdlane(W0t.y, 0);
        float t2s = rdlane(W0t.z, 0);
        float t3s = rdlane(W0t.w, 0);
        racc[0] = fmaf(t0s, W0t.x, racc[0]); bacc[0] = fmaf(t0s, W0r.x, bacc[0]);
        racc[1] = fmaf(t0s, W0t.y, racc[1]); bacc[1] = fmaf(t0s, W0r.y, bacc[1]);
        racc[2] = fmaf(t0s, W0t.z, racc[2]); bacc[2] = fmaf(t0s, W0r.z, bacc[2]);
        racc[3] = fmaf(t0s, W0t.w, racc[3]); bacc[3] = fmaf(t0s, W0r.w, bacc[3]);
        racc[0] = fmaf(t1s, W0t.y, racc[0]); bacc[0] = fmaf(t1s, W0r.y, bacc[0]);
        racc[1] = fmaf(t1s, W0t.z, racc[1]); bacc[1] = fmaf(t1s, W0r.z, bacc[1]);
        racc[2] = fmaf(t1s, W0t.w, racc[2]); bacc[2] = fmaf(t1s, W0r.w, bacc[2]);
        racc[3] = fmaf(t1s, W1t.x, racc[3]); bacc[3] = fmaf(t1s, W1r.x, bacc[3]);
        racc[0] = fmaf(t2s, W0t.z, racc[0]); bacc[0] = fmaf(t2s, W0r.z, bacc[0]);
        racc[1] = fmaf(t2s, W0t.w, racc[1]); bacc[1] = fmaf(t2s, W0r.w, bacc[1]);
        racc[2] = fmaf(t2s, W1t.x, racc[2]); bacc[2] = fmaf(t2s, W1r.x, bacc[2]);
        racc[3] = fmaf(t2s, W1t.y, racc[3]); bacc[3] = fmaf(t2s, W1r.y, bacc[3]);
        racc[0] = fmaf(t3s, W0t.w, racc[0]); bacc[0] = fmaf(t3s, W0r.w, bacc[0]);
        racc[1] = fmaf(t3s, W1t.x, racc[1]); bacc[1] = fmaf(t3s, W1r.x, bacc[1]);
        racc[2] = fmaf(t3s, W1t.y, racc[2]); bacc[2] = fmaf(t3s, W1r.y, bacc[2]);
        racc[3] = fmaf(t3s, W1t.z, racc[3]); bacc[3] = fmaf(t3s, W1r.z, bacc[3]);
        W0t = W1t; W0r = W1r;
    }

    // --- normalize; init Schur state directly in lane-major registers ---
    float t0v = rdlane(racc[0], 0) + EPS;
    float it0 = frcp_nr(t0v);
    float F[4], Bv[4], av[4], rav[4], xv[4], Rv[4];
    #pragma unroll
    for (int c = 0; c < 4; ++c) {
        float rh = racc[c] * it0;
        if (c == 0) rh = l0 ? 1.0f : rh;   // rho[0] = (r0+eps)/t0 = 1 exactly
        F[c] = rh; Bv[c] = rh;
    }
    float bb0 = rdlane(bacc[0], 0) * it0;
    #pragma unroll
    for (int c = 0; c < 4; ++c) {
        float bvv = bacc[c] * it0;
        Rv[c] = fmaf(-bb0, F[c], bvv);     // R_0 = bb - bb0*rho
        xv[c] = 0.f; av[c] = 0.f; rav[c] = 0.f;
    }
    if (l0) { xv[0] = bb0; av[0] = 1.0f; rav[0] = 1.0f; }

    float sF  = rdlane(F[1], 0);           // F_0[1] = rho[1]
    float sB  = 1.0f, isB = 1.0f;
    float sR  = rdlane(Rv[1], 0);          // R_0[1]

    // --- 255 Schur steps, FULLY unrolled: literal lane indices everywhere,
    //     one giant basic block -> scheduler pipelines across steps ---
    #pragma unroll
    for (int t = 0; t < 63; ++t) {
        STEP(1, 2, t, t);                  // k = 4t
        STEP(2, 3, t, t);                  // k = 4t+1
        STEP(3, 0, t, t + 1);              // k = 4t+2
        STEP(0, 1, t + 1, t + 1);          // k = 4t+3
    }
    STEP(1, 2, 63, 63);                    // k = 252
    STEP(2, 3, 63, 63);                    // k = 253
    {   // k = 254: only mu and the x update matter
        float g  = -sF * isB;
        float sE = fmaf(g, sF, sB);
        float mu = sR * frcp_fast(sE);
        float sr0 = dpp0<0x138>(rav[3]);
        xv[0] = fmaf(mu, fmaf(g, av[0], sr0),    xv[0]);
        xv[1] = fmaf(mu, fmaf(g, av[1], rav[0]), xv[1]);
        xv[2] = fmaf(mu, fmaf(g, av[2], rav[1]), xv[2]);
        xv[3] = fmaf(mu, fmaf(g, av[3], rav[2]), xv[3]);
    }

    // --- loss: 0.5*sqrt(sum((T*v)^2)/sum(v^2)), elements e = 4*lane+c ---
    float sT = 0.f, sV = 0.f;
    const float dxg = 20.0f / 255.0f;
    #pragma unroll
    for (int c = 0; c < 4; ++c) {
        float v  = xv[c];
        float u  = -10.0f + dxg * (float)(4*lane + c) + 0.5f * dxg;
        float Ti = 1.0f - expf(-0.5f * u * u);   // T normalizers == 1.0f in f32
        float tw = Ti * v;
        sT += tw * tw;
        sV += v * v;
    }
    wave_red_sum2(sT, sV);
    if (l0) losses[b] = 0.5f * sqrtf(sT / sV);
}

// deterministic final reduction of 512 per-batch losses
__global__ __launch_bounds__(64) void awloss_reduce(
        const float* __restrict__ losses, float* __restrict__ out) {
    int lane = threadIdx.x;
    float s = 0.f;
    #pragma unroll
    for (int c = 0; c < 8; ++c) s += losses[c * 64 + lane];
    float d = 0.f;
    wave_red_sum2(s, d);
    if (lane == 0) out[0] = s;
}

extern "C" void kernel_launch(void* const* d_in, const int* in_sizes, int n_in,
                              void* d_out, int out_size, void* d_ws, size_t ws_size,
                              hipStream_t stream) {
    const float* recon  = (const float*)d_in[0];
    const float* target = (const float*)d_in[1];
    float* losses = (float*)d_ws;   // 512 floats
    float* out    = (float*)d_out;

    awloss_batch<<<512, 64, 0, stream>>>(recon, target, losses);
    awloss_reduce<<<1, 64, 0, stream>>>(losses, out);
}